// Round 5
// baseline (821.043 us; speedup 1.0000x reference)
//
#include <hip/hip_runtime.h>
#include <hip/hip_bf16.h>
#include <math.h>

#define KD 1024
#define VD 50000
#define BD 2048
#define WDIM 20
#define THRV 1e-10f
#define PI_F 3.14159274101257324f  /* 0x40490FDB — f32(pi) */

// d_out is FLOAT32[2049]: [0..2048) = mu (as float), [2048] = E.
// (Established round 4: all-zero output gives absmax 1024 = max bf16(mu_ref),
//  not |E|~31785; and bf16 writes produced mu-independent absmax 1020 —
//  exactly the zeros-tail signature of a half-filled float32 buffer.)

// ---------------------------------------------------------------------------
// Kernel 1: scores + argmax per batch — numpy-float32 emulation.
// score[b,k] = sum_w ( |Wc[k,id]| + |angle(Wc[k,id]*conj(e^{i pi pos}))| )
// pairwise-8 numpy sum order; ties -> smallest k.
// ---------------------------------------------------------------------------
__global__ __launch_bounds__(1024) void scores_kernel(
    const float* __restrict__ W,
    const float* __restrict__ pos,
    const int*   __restrict__ ids,
    float* __restrict__ out,          // float32 output
    int* __restrict__ mu_int)
{
    __shared__ int   s_id[WDIM];
    __shared__ float s_c[WDIM];
    __shared__ float s_s[WDIM];
    __shared__ float r_val[16];
    __shared__ int   r_idx[16];

    const int b = blockIdx.x;
    const int t = threadIdx.x;

    if (t < WDIM) {
        s_id[t] = ids[b * WDIM + t];
        const float pf = __fmul_rn(pos[b * WDIM + t], PI_F);
        s_c[t] = cosf(pf);
        s_s[t] = sinf(pf);
    }
    __syncthreads();

    const float* Wk = W + (size_t)t * (VD * 2);
    float phi[WDIM];
#pragma unroll
    for (int w = 0; w < WDIM; ++w) {
        const float2 g = *reinterpret_cast<const float2*>(Wk + 2 * (size_t)s_id[w]);
        const float c = s_c[w], s = s_s[w];
        const float mag = hypotf(g.x, g.y);
        const float re = __fadd_rn(__fmul_rn(g.x, c), __fmul_rn(g.y, s));
        const float im = __fsub_rn(__fmul_rn(g.y, c), __fmul_rn(g.x, s));
        phi[w] = __fadd_rn(mag, fabsf(atan2f(im, re)));
    }

    // numpy pairwise_sum order for n=20
    const float r0 = __fadd_rn(phi[0], phi[8]);
    const float r1 = __fadd_rn(phi[1], phi[9]);
    const float r2 = __fadd_rn(phi[2], phi[10]);
    const float r3 = __fadd_rn(phi[3], phi[11]);
    const float r4 = __fadd_rn(phi[4], phi[12]);
    const float r5 = __fadd_rn(phi[5], phi[13]);
    const float r6 = __fadd_rn(phi[6], phi[14]);
    const float r7 = __fadd_rn(phi[7], phi[15]);
    float score = __fadd_rn(__fadd_rn(__fadd_rn(r0, r1), __fadd_rn(r2, r3)),
                            __fadd_rn(__fadd_rn(r4, r5), __fadd_rn(r6, r7)));
    score = __fadd_rn(score, phi[16]);
    score = __fadd_rn(score, phi[17]);
    score = __fadd_rn(score, phi[18]);
    score = __fadd_rn(score, phi[19]);

    // argmax: larger score wins, tie -> smaller k
    float v = score; int vi = t;
#pragma unroll
    for (int off = 32; off > 0; off >>= 1) {
        float ov = __shfl_down(v, off, 64);
        int   oi = __shfl_down(vi, off, 64);
        if (ov > v || (ov == v && oi < vi)) { v = ov; vi = oi; }
    }
    if ((t & 63) == 0) { r_val[t >> 6] = v; r_idx[t >> 6] = vi; }
    __syncthreads();
    if (t == 0) {
        float bv = r_val[0]; int bi = r_idx[0];
#pragma unroll
        for (int i = 1; i < 16; ++i) {
            if (r_val[i] > bv || (r_val[i] == bv && r_idx[i] < bi)) {
                bv = r_val[i]; bi = r_idx[i];
            }
        }
        mu_int[b] = bi;
        out[b] = (float)bi;
    }
}

// ---------------------------------------------------------------------------
// Kernel 2: norm2[k] = sum_v |Wc[k,v]|^2 (coalesced)
// ---------------------------------------------------------------------------
__global__ __launch_bounds__(512) void norm_kernel(
    const float* __restrict__ W,
    float* __restrict__ norm2)
{
    const int k = blockIdx.x;
    const float4* row = reinterpret_cast<const float4*>(W + (size_t)k * (VD * 2));
    const int n4 = (VD * 2) / 4;
    float acc = 0.0f;
    for (int i = threadIdx.x; i < n4; i += 512) {
        float4 v = row[i];
        acc += v.x * v.x + v.y * v.y + v.z * v.z + v.w * v.w;
    }
    __shared__ float sm[8];
#pragma unroll
    for (int off = 32; off > 0; off >>= 1) acc += __shfl_down(acc, off, 64);
    if ((threadIdx.x & 63) == 0) sm[threadIdx.x >> 6] = acc;
    __syncthreads();
    if (threadIdx.x == 0) {
        float s = 0.0f;
#pragma unroll
        for (int i = 0; i < 8; ++i) s += sm[i];
        norm2[k] = s;
    }
}

// ---------------------------------------------------------------------------
// Kernel 3: per-batch energy contribution
// ---------------------------------------------------------------------------
__global__ __launch_bounds__(64) void e_kernel(
    const float* __restrict__ W,
    const float* __restrict__ Ps,
    const float* __restrict__ pos,
    const int*   __restrict__ ids,
    const int*   __restrict__ mu_int,
    const float* __restrict__ norm2,
    float* __restrict__ contrib)
{
    const int b = blockIdx.x;
    const int t = threadIdx.x;
    const int mu = mu_int[b];
    const float* Wm = W + (size_t)mu * (VD * 2);

    float loc_abs = 0.0f, loc_phi = 0.0f;
    if (t < WDIM) {
        const int id = ids[b * WDIM + t];
        const float P = Ps[b * WDIM + t];
        const float pf = __fmul_rn(pos[b * WDIM + t], PI_F);
        const float c = cosf(pf), s = sinf(pf);
        const float2 g = *reinterpret_cast<const float2*>(Wm + 2 * (size_t)id);
        // alpha = Wc[mu,id] * conj(Ps * or) = Ps * (g * conj(or))
        float re = P * (g.x * c + g.y * s);
        float im = P * (g.y * c - g.x * s);
        if (re < THRV && re > -THRV) re = THRV;
        if (im < THRV && im > -THRV) im = THRV;
        loc_abs = sqrtf(re * re + im * im);
        loc_phi = fabsf(atan2f(im, re)) * P;
    }
#pragma unroll
    for (int off = 32; off > 0; off >>= 1) {
        loc_abs += __shfl_down(loc_abs, off, 64);
        loc_phi += __shfl_down(loc_phi, off, 64);
    }
    if (t == 0) {
        const float den = sqrtf(norm2[mu]);
        contrib[b] = loc_abs / den + loc_phi;
    }
}

// ---------------------------------------------------------------------------
// Kernel 4: deterministic final reduction (f64 accum), E -> out[2048] (f32)
// ---------------------------------------------------------------------------
__global__ __launch_bounds__(256) void finalize_kernel(
    const float* __restrict__ contrib,
    float* __restrict__ out)
{
    __shared__ double sm[4];
    double acc = 0.0;
    for (int i = threadIdx.x; i < BD; i += 256) acc += (double)contrib[i];
#pragma unroll
    for (int off = 32; off > 0; off >>= 1) acc += __shfl_down(acc, off, 64);
    if ((threadIdx.x & 63) == 0) sm[threadIdx.x >> 6] = acc;
    __syncthreads();
    if (threadIdx.x == 0) {
        double s = sm[0] + sm[1] + sm[2] + sm[3];
        out[BD] = (float)(-s);
    }
}

extern "C" void kernel_launch(void* const* d_in, const int* in_sizes, int n_in,
                              void* d_out, int out_size, void* d_ws, size_t ws_size,
                              hipStream_t stream) {
    const float* W   = (const float*)d_in[0];  // (K, V, 2) fp32
    const float* Ps  = (const float*)d_in[1];  // (B, WD) fp32  (dict order)
    const float* pos = (const float*)d_in[2];  // (B, WD) fp32
    const int*   ids = (const int*)d_in[3];    // (B, WD) int32

    float* out = (float*)d_out;                // float32[2049]

    int*   mu_int  = (int*)d_ws;
    float* contrib = (float*)((char*)d_ws + BD * sizeof(int));
    float* norm2   = (float*)((char*)d_ws + 2 * BD * sizeof(int));

    scores_kernel<<<BD, 1024, 0, stream>>>(W, pos, ids, out, mu_int);
    norm_kernel<<<KD, 512, 0, stream>>>(W, norm2);
    e_kernel<<<BD, 64, 0, stream>>>(W, Ps, pos, ids, mu_int, norm2, contrib);
    finalize_kernel<<<1, 256, 0, stream>>>(contrib, out);
}

// Round 6
// 661.788 us; speedup vs baseline: 1.2406x; 1.2406x over previous
//
#include <hip/hip_runtime.h>
#include <hip/hip_bf16.h>
#include <math.h>

#define KD 1024
#define VD 50000
#define BD 2048
#define WDIM 20
#define THRV 1e-10f
#define PI_F 3.14159274101257324f  /* 0x40490FDB — f32(pi) */

#define GRID_ROWS 512
#define BLK 512

// d_out is FLOAT32[2049]: [0..2048) = mu (as float), [2048] = E.

// ---------------------------------------------------------------------------
// Kernel A: precompute cos/sin(pi*pos) tables (B*WD entries)
// ---------------------------------------------------------------------------
__global__ __launch_bounds__(256) void trig_kernel(
    const float* __restrict__ pos, float* __restrict__ tc, float* __restrict__ ts)
{
    const int i = blockIdx.x * 256 + threadIdx.x;
    if (i < BD * WDIM) {
        const float pf = __fmul_rn(pos[i], PI_F);
        tc[i] = cosf(pf);
        ts[i] = sinf(pf);
    }
}

// ---------------------------------------------------------------------------
// Kernel B: block per W row k (2 rows per block). Phase 1 streams the row
// coalesced (norm^2 reduction, warms L2/LLC); phase 2 computes score[k][b]
// for all b with gathers that hit the cached row. Active set = 512 rows
// x 400 KB = 200 MB < 256 MB LLC.
// Score math is bit-identical to the passing round (same _rn ops, numpy
// pairwise-8 sum order), so mu is unchanged.
// ---------------------------------------------------------------------------
__global__ __launch_bounds__(BLK) void row_kernel(
    const float* __restrict__ W,
    const int*   __restrict__ ids,
    const float* __restrict__ tc,
    const float* __restrict__ ts,
    float* __restrict__ norm2,
    float* __restrict__ scores)   // [KD][BD]
{
    __shared__ float sm[BLK / 64];

    for (int rep = 0; rep < KD / GRID_ROWS; ++rep) {
        const int k = blockIdx.x + GRID_ROWS * rep;
        const float* Wk = W + (size_t)k * (VD * 2);

        // ---- phase 1: coalesced row stream + norm2 partial ----
        const float4* row4 = reinterpret_cast<const float4*>(Wk);
        float acc = 0.0f;
        for (int i = threadIdx.x; i < (VD * 2) / 4; i += BLK) {
            const float4 v = row4[i];
            acc += v.x * v.x + v.y * v.y + v.z * v.z + v.w * v.w;
        }
#pragma unroll
        for (int off = 32; off > 0; off >>= 1) acc += __shfl_down(acc, off, 64);
        if ((threadIdx.x & 63) == 0) sm[threadIdx.x >> 6] = acc;
        __syncthreads();
        if (threadIdx.x == 0) {
            float s = 0.0f;
#pragma unroll
            for (int i = 0; i < BLK / 64; ++i) s += sm[i];
            norm2[k] = s;
        }

        // ---- phase 2: scores for all b (gathers now cache-resident) ----
        for (int b = threadIdx.x; b < BD; b += BLK) {
            const int base = b * WDIM;
            float phi[WDIM];
#pragma unroll
            for (int w = 0; w < WDIM; ++w) {
                const int   id = ids[base + w];
                const float c  = tc[base + w];
                const float s  = ts[base + w];
                const float2 g = *reinterpret_cast<const float2*>(Wk + 2 * (size_t)id);
                const float mag = hypotf(g.x, g.y);
                const float re  = __fadd_rn(__fmul_rn(g.x, c), __fmul_rn(g.y, s));
                const float im  = __fsub_rn(__fmul_rn(g.y, c), __fmul_rn(g.x, s));
                phi[w] = __fadd_rn(mag, fabsf(atan2f(im, re)));
            }
            // numpy pairwise_sum order for n=20
            const float r0 = __fadd_rn(phi[0], phi[8]);
            const float r1 = __fadd_rn(phi[1], phi[9]);
            const float r2 = __fadd_rn(phi[2], phi[10]);
            const float r3 = __fadd_rn(phi[3], phi[11]);
            const float r4 = __fadd_rn(phi[4], phi[12]);
            const float r5 = __fadd_rn(phi[5], phi[13]);
            const float r6 = __fadd_rn(phi[6], phi[14]);
            const float r7 = __fadd_rn(phi[7], phi[15]);
            float score = __fadd_rn(__fadd_rn(__fadd_rn(r0, r1), __fadd_rn(r2, r3)),
                                    __fadd_rn(__fadd_rn(r4, r5), __fadd_rn(r6, r7)));
            score = __fadd_rn(score, phi[16]);
            score = __fadd_rn(score, phi[17]);
            score = __fadd_rn(score, phi[18]);
            score = __fadd_rn(score, phi[19]);
            scores[(size_t)k * BD + b] = score;
        }
        __syncthreads(); // sm reused next rep
    }
}

// ---------------------------------------------------------------------------
// Kernel C: argmax over k per batch (coalesced: lane b reads scores[k][b]).
// Same semantics as before: strict >, tie -> smallest k.
// ---------------------------------------------------------------------------
__global__ __launch_bounds__(256) void argmax_kernel(
    const float* __restrict__ scores,
    float* __restrict__ out,
    int*   __restrict__ mu_int)
{
    const int b = blockIdx.x * 256 + threadIdx.x;
    float best = -3.402823466e+38f;
    int   bi   = 0;
    for (int k = 0; k < KD; ++k) {
        const float v = scores[(size_t)k * BD + b];
        if (v > best) { best = v; bi = k; }
    }
    mu_int[b] = bi;
    out[b] = (float)bi;
}

// ---------------------------------------------------------------------------
// Kernel D: per-batch energy contribution (unchanged from passing round)
// ---------------------------------------------------------------------------
__global__ __launch_bounds__(64) void e_kernel(
    const float* __restrict__ W,
    const float* __restrict__ Ps,
    const float* __restrict__ pos,
    const int*   __restrict__ ids,
    const int*   __restrict__ mu_int,
    const float* __restrict__ norm2,
    float* __restrict__ contrib)
{
    const int b = blockIdx.x;
    const int t = threadIdx.x;
    const int mu = mu_int[b];
    const float* Wm = W + (size_t)mu * (VD * 2);

    float loc_abs = 0.0f, loc_phi = 0.0f;
    if (t < WDIM) {
        const int id = ids[b * WDIM + t];
        const float P = Ps[b * WDIM + t];
        const float pf = __fmul_rn(pos[b * WDIM + t], PI_F);
        const float c = cosf(pf), s = sinf(pf);
        const float2 g = *reinterpret_cast<const float2*>(Wm + 2 * (size_t)id);
        float re = P * (g.x * c + g.y * s);
        float im = P * (g.y * c - g.x * s);
        if (re < THRV && re > -THRV) re = THRV;
        if (im < THRV && im > -THRV) im = THRV;
        loc_abs = sqrtf(re * re + im * im);
        loc_phi = fabsf(atan2f(im, re)) * P;
    }
#pragma unroll
    for (int off = 32; off > 0; off >>= 1) {
        loc_abs += __shfl_down(loc_abs, off, 64);
        loc_phi += __shfl_down(loc_phi, off, 64);
    }
    if (t == 0) {
        const float den = sqrtf(norm2[mu]);
        contrib[b] = loc_abs / den + loc_phi;
    }
}

// ---------------------------------------------------------------------------
// Kernel E: deterministic final reduction (f64 accum), E -> out[2048]
// ---------------------------------------------------------------------------
__global__ __launch_bounds__(256) void finalize_kernel(
    const float* __restrict__ contrib,
    float* __restrict__ out)
{
    __shared__ double sm[4];
    double acc = 0.0;
    for (int i = threadIdx.x; i < BD; i += 256) acc += (double)contrib[i];
#pragma unroll
    for (int off = 32; off > 0; off >>= 1) acc += __shfl_down(acc, off, 64);
    if ((threadIdx.x & 63) == 0) sm[threadIdx.x >> 6] = acc;
    __syncthreads();
    if (threadIdx.x == 0) {
        double s = sm[0] + sm[1] + sm[2] + sm[3];
        out[BD] = (float)(-s);
    }
}

// ---------------------------------------------------------------------------
// Fallback (round-5 passing path) if ws_size is too small for the scores mat
// ---------------------------------------------------------------------------
__global__ __launch_bounds__(1024) void scores_kernel_fb(
    const float* __restrict__ W,
    const float* __restrict__ pos,
    const int*   __restrict__ ids,
    float* __restrict__ out,
    int* __restrict__ mu_int)
{
    __shared__ int   s_id[WDIM];
    __shared__ float s_c[WDIM];
    __shared__ float s_s[WDIM];
    __shared__ float r_val[16];
    __shared__ int   r_idx[16];

    const int b = blockIdx.x;
    const int t = threadIdx.x;

    if (t < WDIM) {
        s_id[t] = ids[b * WDIM + t];
        const float pf = __fmul_rn(pos[b * WDIM + t], PI_F);
        s_c[t] = cosf(pf);
        s_s[t] = sinf(pf);
    }
    __syncthreads();

    const float* Wk = W + (size_t)t * (VD * 2);
    float phi[WDIM];
#pragma unroll
    for (int w = 0; w < WDIM; ++w) {
        const float2 g = *reinterpret_cast<const float2*>(Wk + 2 * (size_t)s_id[w]);
        const float c = s_c[w], s = s_s[w];
        const float mag = hypotf(g.x, g.y);
        const float re = __fadd_rn(__fmul_rn(g.x, c), __fmul_rn(g.y, s));
        const float im = __fsub_rn(__fmul_rn(g.y, c), __fmul_rn(g.x, s));
        phi[w] = __fadd_rn(mag, fabsf(atan2f(im, re)));
    }
    const float r0 = __fadd_rn(phi[0], phi[8]);
    const float r1 = __fadd_rn(phi[1], phi[9]);
    const float r2 = __fadd_rn(phi[2], phi[10]);
    const float r3 = __fadd_rn(phi[3], phi[11]);
    const float r4 = __fadd_rn(phi[4], phi[12]);
    const float r5 = __fadd_rn(phi[5], phi[13]);
    const float r6 = __fadd_rn(phi[6], phi[14]);
    const float r7 = __fadd_rn(phi[7], phi[15]);
    float score = __fadd_rn(__fadd_rn(__fadd_rn(r0, r1), __fadd_rn(r2, r3)),
                            __fadd_rn(__fadd_rn(r4, r5), __fadd_rn(r6, r7)));
    score = __fadd_rn(score, phi[16]);
    score = __fadd_rn(score, phi[17]);
    score = __fadd_rn(score, phi[18]);
    score = __fadd_rn(score, phi[19]);

    float v = score; int vi = t;
#pragma unroll
    for (int off = 32; off > 0; off >>= 1) {
        float ov = __shfl_down(v, off, 64);
        int   oi = __shfl_down(vi, off, 64);
        if (ov > v || (ov == v && oi < vi)) { v = ov; vi = oi; }
    }
    if ((t & 63) == 0) { r_val[t >> 6] = v; r_idx[t >> 6] = vi; }
    __syncthreads();
    if (t == 0) {
        float bv = r_val[0]; int bi = r_idx[0];
#pragma unroll
        for (int i = 1; i < 16; ++i) {
            if (r_val[i] > bv || (r_val[i] == bv && r_idx[i] < bi)) {
                bv = r_val[i]; bi = r_idx[i];
            }
        }
        mu_int[b] = bi;
        out[b] = (float)bi;
    }
}

__global__ __launch_bounds__(512) void norm_kernel_fb(
    const float* __restrict__ W,
    float* __restrict__ norm2)
{
    const int k = blockIdx.x;
    const float4* row = reinterpret_cast<const float4*>(W + (size_t)k * (VD * 2));
    const int n4 = (VD * 2) / 4;
    float acc = 0.0f;
    for (int i = threadIdx.x; i < n4; i += 512) {
        float4 v = row[i];
        acc += v.x * v.x + v.y * v.y + v.z * v.z + v.w * v.w;
    }
    __shared__ float sm[8];
#pragma unroll
    for (int off = 32; off > 0; off >>= 1) acc += __shfl_down(acc, off, 64);
    if ((threadIdx.x & 63) == 0) sm[threadIdx.x >> 6] = acc;
    __syncthreads();
    if (threadIdx.x == 0) {
        float s = 0.0f;
#pragma unroll
        for (int i = 0; i < 8; ++i) s += sm[i];
        norm2[k] = s;
    }
}

extern "C" void kernel_launch(void* const* d_in, const int* in_sizes, int n_in,
                              void* d_out, int out_size, void* d_ws, size_t ws_size,
                              hipStream_t stream) {
    const float* W   = (const float*)d_in[0];  // (K, V, 2) fp32
    const float* Ps  = (const float*)d_in[1];  // (B, WD) fp32
    const float* pos = (const float*)d_in[2];  // (B, WD) fp32
    const int*   ids = (const int*)d_in[3];    // (B, WD) int32

    float* out = (float*)d_out;                // float32[2049]

    // ws layout
    float* tc      = (float*)d_ws;                       // B*WD
    float* ts      = tc + BD * WDIM;                     // B*WD
    float* norm2   = ts + BD * WDIM;                     // KD
    float* contrib = norm2 + KD;                         // BD
    int*   mu_int  = (int*)(contrib + BD);               // BD
    float* scores  = (float*)(mu_int + BD);              // KD*BD
    const size_t need = ((size_t)(2 * BD * WDIM + KD + BD + BD) +
                         (size_t)KD * BD) * 4;

    if (ws_size >= need) {
        trig_kernel<<<(BD * WDIM + 255) / 256, 256, 0, stream>>>(pos, tc, ts);
        row_kernel<<<GRID_ROWS, BLK, 0, stream>>>(W, ids, tc, ts, norm2, scores);
        argmax_kernel<<<BD / 256, 256, 0, stream>>>(scores, out, mu_int);
    } else {
        scores_kernel_fb<<<BD, 1024, 0, stream>>>(W, pos, ids, out, mu_int);
        norm_kernel_fb<<<KD, 512, 0, stream>>>(W, norm2);
    }
    e_kernel<<<BD, 64, 0, stream>>>(W, Ps, pos, ids, mu_int, norm2, contrib);
    finalize_kernel<<<1, 256, 0, stream>>>(contrib, out);
}

// Round 7
// 222.558 us; speedup vs baseline: 3.6891x; 2.9736x over previous
//
#include <hip/hip_runtime.h>
#include <hip/hip_bf16.h>
#include <math.h>

#define KD 1024
#define VD 50000
#define BD 2048
#define WDIM 20
#define THRV 1e-10f
#define PI_F 3.14159274101257324f  /* 0x40490FDB — f32(pi) */

#define NCHUNK 4
#define CHUNK 12500              /* complex elements per chunk; 4*12500 = VD */

// d_out is FLOAT32[2049]: [0..2048) = mu (as float), [2048] = E.

// ---------------------------------------------------------------------------
// Kernel P: precompute b-minor tables.
//   cst[w][b]  = (cos(pi*pos[b][w]), sin(pi*pos[b][w]))   (float2, coalesced)
//   idp[j][b]  = ids[b][2j] | ids[b][2j+1]<<16            (u32, coalesced)
// Same trig ops as the passing round -> bit-identical scores.
// ---------------------------------------------------------------------------
__global__ __launch_bounds__(256) void prep_kernel(
    const float* __restrict__ pos,
    const int*   __restrict__ ids,
    float2* __restrict__ cst,
    unsigned int* __restrict__ idp)
{
    const int b = blockIdx.x * 256 + threadIdx.x;
    if (b >= BD) return;
    int idv[WDIM];
#pragma unroll
    for (int w = 0; w < WDIM; ++w) {
        idv[w] = ids[b * WDIM + w];
        const float pf = __fmul_rn(pos[b * WDIM + w], PI_F);
        cst[w * BD + b] = make_float2(cosf(pf), sinf(pf));
    }
#pragma unroll
    for (int j = 0; j < WDIM / 2; ++j)
        idp[j * BD + b] = (unsigned int)idv[2 * j] |
                          ((unsigned int)idv[2 * j + 1] << 16);
}

// ---------------------------------------------------------------------------
// Kernel B: one block per W row k. Stream the row through LDS in 4 chunks
// (coalesced; W read exactly once; norm2 fused). Gathers are LDS reads.
// The divergent chunk-match phase only COPIES float2 -> registers; the
// hypot/atan2 math runs once afterwards, divergence-free, in exact numpy
// pairwise-8 order (bit-identical to the passing round).
// ---------------------------------------------------------------------------
__global__ __launch_bounds__(1024, 4) void row_kernel(
    const float* __restrict__ W,
    const unsigned int* __restrict__ idp,
    const float2* __restrict__ cst,
    float* __restrict__ norm2,
    float* __restrict__ scores)   // [KD][BD]
{
    __shared__ __align__(16) float chunk[CHUNK * 2];   // 100 KB
    __shared__ float sm[16];

    const int k = blockIdx.x;
    const int t = threadIdx.x;
    const float* Wk = W + (size_t)k * (VD * 2);

    // per-thread ids for b = t and b = t + 1024 (packed u16 pairs)
    unsigned int idreg[2][WDIM / 2];
#pragma unroll
    for (int j = 0; j < WDIM / 2; ++j) {
        idreg[0][j] = idp[j * BD + t];
        idreg[1][j] = idp[j * BD + t + 1024];
    }

    float gx[2][WDIM], gy[2][WDIM];
#pragma unroll
    for (int w = 0; w < WDIM; ++w) {
        gx[0][w] = 0.f; gy[0][w] = 0.f; gx[1][w] = 0.f; gy[1][w] = 0.f;
    }

    float nacc = 0.0f;

    for (int c = 0; c < NCHUNK; ++c) {
        __syncthreads();   // protect chunk from previous iteration's readers
        // ---- coalesced chunk stream + norm2 partial ----
        const float4* src = reinterpret_cast<const float4*>(Wk + c * (CHUNK * 2));
        float4* dst = reinterpret_cast<float4*>(chunk);
        for (int i = t; i < (CHUNK * 2) / 4; i += 1024) {
            const float4 v = src[i];
            dst[i] = v;
            nacc += v.x * v.x + v.y * v.y + v.z * v.z + v.w * v.w;
        }
        __syncthreads();

        // ---- match phase: copy g for ids inside this chunk ----
        const int lo = c * CHUNK;
#pragma unroll
        for (int bb = 0; bb < 2; ++bb) {
#pragma unroll
            for (int w = 0; w < WDIM; ++w) {
                const int id  = (int)((idreg[bb][w >> 1] >> ((w & 1) * 16)) & 0xFFFFu);
                const int off = id - lo;
                const bool m  = (unsigned)off < (unsigned)CHUNK;
                const int a   = m ? off : 0;
                const float x = chunk[2 * a];
                const float y = chunk[2 * a + 1];
                if (m) { gx[bb][w] = x; gy[bb][w] = y; }
            }
        }
    }

    // ---- norm2 block reduction ----
#pragma unroll
    for (int off = 32; off > 0; off >>= 1) nacc += __shfl_down(nacc, off, 64);
    if ((t & 63) == 0) sm[t >> 6] = nacc;
    __syncthreads();
    if (t == 0) {
        float s = 0.0f;
#pragma unroll
        for (int i = 0; i < 16; ++i) s += sm[i];
        norm2[k] = s;
    }

    // ---- score math (divergence-free), exact numpy pairwise-8 order ----
#pragma unroll
    for (int bb = 0; bb < 2; ++bb) {
        const int b = t + bb * 1024;
        float phi[WDIM];
#pragma unroll
        for (int w = 0; w < WDIM; ++w) {
            const float2 cs = cst[w * BD + b];
            const float x = gx[bb][w], y = gy[bb][w];
            const float mag = hypotf(x, y);
            const float re  = __fadd_rn(__fmul_rn(x, cs.x), __fmul_rn(y, cs.y));
            const float im  = __fsub_rn(__fmul_rn(y, cs.x), __fmul_rn(x, cs.y));
            phi[w] = __fadd_rn(mag, fabsf(atan2f(im, re)));
        }
        const float r0 = __fadd_rn(phi[0], phi[8]);
        const float r1 = __fadd_rn(phi[1], phi[9]);
        const float r2 = __fadd_rn(phi[2], phi[10]);
        const float r3 = __fadd_rn(phi[3], phi[11]);
        const float r4 = __fadd_rn(phi[4], phi[12]);
        const float r5 = __fadd_rn(phi[5], phi[13]);
        const float r6 = __fadd_rn(phi[6], phi[14]);
        const float r7 = __fadd_rn(phi[7], phi[15]);
        float score = __fadd_rn(__fadd_rn(__fadd_rn(r0, r1), __fadd_rn(r2, r3)),
                                __fadd_rn(__fadd_rn(r4, r5), __fadd_rn(r6, r7)));
        score = __fadd_rn(score, phi[16]);
        score = __fadd_rn(score, phi[17]);
        score = __fadd_rn(score, phi[18]);
        score = __fadd_rn(score, phi[19]);
        scores[(size_t)k * BD + b] = score;
    }
}

// ---------------------------------------------------------------------------
// Kernel C: argmax over k per batch (coalesced). Strict >, tie -> smallest k.
// ---------------------------------------------------------------------------
__global__ __launch_bounds__(256) void argmax_kernel(
    const float* __restrict__ scores,
    float* __restrict__ out,
    int*   __restrict__ mu_int)
{
    const int b = blockIdx.x * 256 + threadIdx.x;
    float best = -3.402823466e+38f;
    int   bi   = 0;
    for (int k = 0; k < KD; ++k) {
        const float v = scores[(size_t)k * BD + b];
        if (v > best) { best = v; bi = k; }
    }
    mu_int[b] = bi;
    out[b] = (float)bi;
}

// ---------------------------------------------------------------------------
// Kernel D: per-batch energy contribution
// ---------------------------------------------------------------------------
__global__ __launch_bounds__(64) void e_kernel(
    const float* __restrict__ W,
    const float* __restrict__ Ps,
    const float* __restrict__ pos,
    const int*   __restrict__ ids,
    const int*   __restrict__ mu_int,
    const float* __restrict__ norm2,
    float* __restrict__ contrib)
{
    const int b = blockIdx.x;
    const int t = threadIdx.x;
    const int mu = mu_int[b];
    const float* Wm = W + (size_t)mu * (VD * 2);

    float loc_abs = 0.0f, loc_phi = 0.0f;
    if (t < WDIM) {
        const int id = ids[b * WDIM + t];
        const float P = Ps[b * WDIM + t];
        const float pf = __fmul_rn(pos[b * WDIM + t], PI_F);
        const float c = cosf(pf), s = sinf(pf);
        const float2 g = *reinterpret_cast<const float2*>(Wm + 2 * (size_t)id);
        float re = P * (g.x * c + g.y * s);
        float im = P * (g.y * c - g.x * s);
        if (re < THRV && re > -THRV) re = THRV;
        if (im < THRV && im > -THRV) im = THRV;
        loc_abs = sqrtf(re * re + im * im);
        loc_phi = fabsf(atan2f(im, re)) * P;
    }
#pragma unroll
    for (int off = 32; off > 0; off >>= 1) {
        loc_abs += __shfl_down(loc_abs, off, 64);
        loc_phi += __shfl_down(loc_phi, off, 64);
    }
    if (t == 0) {
        const float den = sqrtf(norm2[mu]);
        contrib[b] = loc_abs / den + loc_phi;
    }
}

// ---------------------------------------------------------------------------
// Kernel E: deterministic final reduction (f64 accum), E -> out[2048]
// ---------------------------------------------------------------------------
__global__ __launch_bounds__(256) void finalize_kernel(
    const float* __restrict__ contrib,
    float* __restrict__ out)
{
    __shared__ double sm[4];
    double acc = 0.0;
    for (int i = threadIdx.x; i < BD; i += 256) acc += (double)contrib[i];
#pragma unroll
    for (int off = 32; off > 0; off >>= 1) acc += __shfl_down(acc, off, 64);
    if ((threadIdx.x & 63) == 0) sm[threadIdx.x >> 6] = acc;
    __syncthreads();
    if (threadIdx.x == 0) {
        double s = sm[0] + sm[1] + sm[2] + sm[3];
        out[BD] = (float)(-s);
    }
}

// ---------------------------------------------------------------------------
// Fallback (round-5 passing path) if ws_size is too small
// ---------------------------------------------------------------------------
__global__ __launch_bounds__(1024) void scores_kernel_fb(
    const float* __restrict__ W,
    const float* __restrict__ pos,
    const int*   __restrict__ ids,
    float* __restrict__ out,
    int* __restrict__ mu_int)
{
    __shared__ int   s_id[WDIM];
    __shared__ float s_c[WDIM];
    __shared__ float s_s[WDIM];
    __shared__ float r_val[16];
    __shared__ int   r_idx[16];

    const int b = blockIdx.x;
    const int t = threadIdx.x;

    if (t < WDIM) {
        s_id[t] = ids[b * WDIM + t];
        const float pf = __fmul_rn(pos[b * WDIM + t], PI_F);
        s_c[t] = cosf(pf);
        s_s[t] = sinf(pf);
    }
    __syncthreads();

    const float* Wk = W + (size_t)t * (VD * 2);
    float phi[WDIM];
#pragma unroll
    for (int w = 0; w < WDIM; ++w) {
        const float2 g = *reinterpret_cast<const float2*>(Wk + 2 * (size_t)s_id[w]);
        const float c = s_c[w], s = s_s[w];
        const float mag = hypotf(g.x, g.y);
        const float re = __fadd_rn(__fmul_rn(g.x, c), __fmul_rn(g.y, s));
        const float im = __fsub_rn(__fmul_rn(g.y, c), __fmul_rn(g.x, s));
        phi[w] = __fadd_rn(mag, fabsf(atan2f(im, re)));
    }
    const float r0 = __fadd_rn(phi[0], phi[8]);
    const float r1 = __fadd_rn(phi[1], phi[9]);
    const float r2 = __fadd_rn(phi[2], phi[10]);
    const float r3 = __fadd_rn(phi[3], phi[11]);
    const float r4 = __fadd_rn(phi[4], phi[12]);
    const float r5 = __fadd_rn(phi[5], phi[13]);
    const float r6 = __fadd_rn(phi[6], phi[14]);
    const float r7 = __fadd_rn(phi[7], phi[15]);
    float score = __fadd_rn(__fadd_rn(__fadd_rn(r0, r1), __fadd_rn(r2, r3)),
                            __fadd_rn(__fadd_rn(r4, r5), __fadd_rn(r6, r7)));
    score = __fadd_rn(score, phi[16]);
    score = __fadd_rn(score, phi[17]);
    score = __fadd_rn(score, phi[18]);
    score = __fadd_rn(score, phi[19]);

    float v = score; int vi = t;
#pragma unroll
    for (int off = 32; off > 0; off >>= 1) {
        float ov = __shfl_down(v, off, 64);
        int   oi = __shfl_down(vi, off, 64);
        if (ov > v || (ov == v && oi < vi)) { v = ov; vi = oi; }
    }
    if ((t & 63) == 0) { r_val[t >> 6] = v; r_idx[t >> 6] = vi; }
    __syncthreads();
    if (t == 0) {
        float bv = r_val[0]; int bi = r_idx[0];
#pragma unroll
        for (int i = 1; i < 16; ++i) {
            if (r_val[i] > bv || (r_val[i] == bv && r_idx[i] < bi)) {
                bv = r_val[i]; bi = r_idx[i];
            }
        }
        mu_int[b] = bi;
        out[b] = (float)bi;
    }
}

__global__ __launch_bounds__(512) void norm_kernel_fb(
    const float* __restrict__ W,
    float* __restrict__ norm2)
{
    const int k = blockIdx.x;
    const float4* row = reinterpret_cast<const float4*>(W + (size_t)k * (VD * 2));
    const int n4 = (VD * 2) / 4;
    float acc = 0.0f;
    for (int i = threadIdx.x; i < n4; i += 512) {
        float4 v = row[i];
        acc += v.x * v.x + v.y * v.y + v.z * v.z + v.w * v.w;
    }
    __shared__ float sm[8];
#pragma unroll
    for (int off = 32; off > 0; off >>= 1) acc += __shfl_down(acc, off, 64);
    if ((threadIdx.x & 63) == 0) sm[threadIdx.x >> 6] = acc;
    __syncthreads();
    if (threadIdx.x == 0) {
        float s = 0.0f;
#pragma unroll
        for (int i = 0; i < 8; ++i) s += sm[i];
        norm2[k] = s;
    }
}

extern "C" void kernel_launch(void* const* d_in, const int* in_sizes, int n_in,
                              void* d_out, int out_size, void* d_ws, size_t ws_size,
                              hipStream_t stream) {
    const float* W   = (const float*)d_in[0];  // (K, V, 2) fp32
    const float* Ps  = (const float*)d_in[1];  // (B, WD) fp32
    const float* pos = (const float*)d_in[2];  // (B, WD) fp32
    const int*   ids = (const int*)d_in[3];    // (B, WD) int32

    float* out = (float*)d_out;                // float32[2049]

    // ws layout
    float2*       cst     = (float2*)d_ws;                         // WD*BD float2
    unsigned int* idp     = (unsigned int*)(cst + WDIM * BD);      // (WD/2)*BD u32
    float*        norm2   = (float*)(idp + (WDIM / 2) * BD);       // KD
    float*        contrib = norm2 + KD;                            // BD
    int*          mu_int  = (int*)(contrib + BD);                  // BD
    float*        scores  = (float*)(mu_int + BD);                 // KD*BD
    const size_t need = (size_t)(WDIM * BD * 2 + (WDIM / 2) * BD + KD + 2 * BD) * 4
                      + (size_t)KD * BD * 4;

    if (ws_size >= need) {
        prep_kernel<<<(BD + 255) / 256, 256, 0, stream>>>(pos, ids, cst, idp);
        row_kernel<<<KD, 1024, 0, stream>>>(W, idp, cst, norm2, scores);
        argmax_kernel<<<BD / 256, 256, 0, stream>>>(scores, out, mu_int);
    } else {
        scores_kernel_fb<<<BD, 1024, 0, stream>>>(W, pos, ids, out, mu_int);
        norm_kernel_fb<<<KD, 512, 0, stream>>>(W, norm2);
    }
    e_kernel<<<BD, 64, 0, stream>>>(W, Ps, pos, ids, mu_int, norm2, contrib);
    finalize_kernel<<<1, 256, 0, stream>>>(contrib, out);
}